// Round 1
// baseline (9476.684 us; speedup 1.0000x reference)
//
#include <hip/hip_runtime.h>
#include <math.h>

#define D 128

// ---------------------------------------------------------------- helpers
__device__ __forceinline__ int lower_bound_i(const int* __restrict__ a, int n, int v) {
    int lo = 0, hi = n;
    while (lo < hi) { int m = (lo + hi) >> 1; if (a[m] < v) lo = m + 1; else hi = m; }
    return lo;
}

// ---------------------------------------------------------------- in-degree counts (once per call)
__global__ void count_kernel(const int* __restrict__ dst, float* __restrict__ cnt, int E) {
    int e = blockIdx.x * blockDim.x + threadIdx.x;
    if (e < E) atomicAdd(&cnt[dst[e]], 1.0f);
}

// ---------------------------------------------------------------- ebar[n][:] /= max(cnt[n],1)  (float4 granules)
__global__ void norm_kernel(float* __restrict__ ebar, const float* __restrict__ cnt, int n4) {
    int i = blockIdx.x * blockDim.x + threadIdx.x;
    if (i < n4) {
        int n = i >> 5;                       // 32 float4 per row of 128
        float inv = 1.0f / fmaxf(cnt[n], 1.0f);
        float4 v = ((const float4*)ebar)[i];
        v.x *= inv; v.y *= inv; v.z *= inv; v.w *= inv;
        ((float4*)ebar)[i] = v;
    }
}

// ---------------------------------------------------------------- edge update GEMM
// tile: 128 edges x 128 cols, K=512 in 16 chunks of 32. 256 thr, 8x8 per thread.
// A row sources per K block: [0,128) node[src], [128,256) node[dst],
// [256,384) edge[e], [384,512) u[batch[src]].
// Epilogue: relu(+bias) -> edge[e][:] in place, atomicAdd into ebar[dst] sum.
__global__ __launch_bounds__(256) void edge_gemm(
    const float* __restrict__ node, float* __restrict__ edge,
    const float* __restrict__ u,
    const int* __restrict__ src, const int* __restrict__ dst,
    const int* __restrict__ batch,
    const float* __restrict__ W, const float* __restrict__ bias,
    float* __restrict__ ebar, int E)
{
    __shared__ float As[128][36];     // +4 pad: row-conflict mitigation, keeps float4 align
    __shared__ float Bs[32][D];
    __shared__ int rs[128], rd[128], rb[128];

    const int tid = threadIdx.x;
    const int e0 = blockIdx.x * 128;

    if (tid < 128) {
        int e = e0 + tid; if (e >= E) e = E - 1;
        int s = src[e];
        rs[tid] = s; rd[tid] = dst[e]; rb[tid] = batch[s];
    }

    float acc[8][8];
#pragma unroll
    for (int i = 0; i < 8; ++i)
#pragma unroll
        for (int j = 0; j < 8; ++j) acc[i][j] = 0.0f;

    const int ar = tid >> 1;           // A-load row 0..127
    const int ac = (tid & 1) * 16;     // A-load col {0,16}
    const int br = tid >> 3;           // B-load row 0..31
    const int bc = (tid & 7) * 16;     // B-load col
    const int ty = tid >> 4;           // out rows ty*8..
    const int tx = tid & 15;           // out cols tx*8..

    int arow_e = e0 + ar; if (arow_e >= E) arow_e = E - 1;

    float bias_r[8];
#pragma unroll
    for (int j = 0; j < 8; ++j) bias_r[j] = bias[tx * 8 + j];

    __syncthreads();                   // rs/rd/rb visible

    for (int c = 0; c < 16; ++c) {
        const int k0 = c * 32;
        const float* abase;
        if (k0 < 128)       abase = node + (size_t)rs[ar] * D + k0;
        else if (k0 < 256)  abase = node + (size_t)rd[ar] * D + (k0 - 128);
        else if (k0 < 384)  abase = edge + (size_t)arow_e * D + (k0 - 256);
        else                abase = u    + (size_t)rb[ar] * D + (k0 - 384);
        float4 av[4];
#pragma unroll
        for (int i = 0; i < 4; ++i) av[i] = *(const float4*)(abase + ac + 4 * i);
        const float* wbase = W + (size_t)(k0 + br) * D + bc;
        float4 bv[4];
#pragma unroll
        for (int i = 0; i < 4; ++i) bv[i] = *(const float4*)(wbase + 4 * i);

        __syncthreads();               // prev chunk compute done
#pragma unroll
        for (int i = 0; i < 4; ++i) *(float4*)&As[ar][ac + 4 * i] = av[i];
#pragma unroll
        for (int i = 0; i < 4; ++i) *(float4*)&Bs[br][bc + 4 * i] = bv[i];
        __syncthreads();               // staging visible

#pragma unroll
        for (int kk = 0; kk < 32; kk += 4) {
            float4 a4[8];
#pragma unroll
            for (int i = 0; i < 8; ++i) a4[i] = *(const float4*)&As[ty * 8 + i][kk];
#pragma unroll
            for (int q = 0; q < 4; ++q) {
                float4 b0 = *(const float4*)&Bs[kk + q][tx * 8];
                float4 b1 = *(const float4*)&Bs[kk + q][tx * 8 + 4];
                float bj[8] = {b0.x, b0.y, b0.z, b0.w, b1.x, b1.y, b1.z, b1.w};
#pragma unroll
                for (int i = 0; i < 8; ++i) {
                    float a = (q == 0) ? a4[i].x : (q == 1) ? a4[i].y : (q == 2) ? a4[i].z : a4[i].w;
#pragma unroll
                    for (int j = 0; j < 8; ++j) acc[i][j] += a * bj[j];
                }
            }
        }
    }

    // epilogue: relu + store + scatter
#pragma unroll
    for (int i = 0; i < 8; ++i) {
        int r = ty * 8 + i;
        int e = e0 + r;
        if (e < E) {
            float v[8];
#pragma unroll
            for (int j = 0; j < 8; ++j) v[j] = fmaxf(acc[i][j] + bias_r[j], 0.0f);
            float* erow = edge + (size_t)e * D + tx * 8;
            *(float4*)(erow)     = make_float4(v[0], v[1], v[2], v[3]);
            *(float4*)(erow + 4) = make_float4(v[4], v[5], v[6], v[7]);
            float* brow = ebar + (size_t)rd[r] * D + tx * 8;
#pragma unroll
            for (int j = 0; j < 8; ++j) atomicAdd(brow + j, v[j]);
        }
    }
}

// ---------------------------------------------------------------- node update GEMM
// tile: 128 nodes x 128 cols, K=384 in 12 chunks.
// A sources: [0,128) node[n], [128,256) ebar[n], [256,384) u[batch[n]].
__global__ __launch_bounds__(256) void node_gemm(
    float* __restrict__ node, const float* __restrict__ ebar,
    const float* __restrict__ u, const int* __restrict__ batch,
    const float* __restrict__ W, const float* __restrict__ bias, int N)
{
    __shared__ float As[128][36];
    __shared__ float Bs[32][D];
    __shared__ int rb[128];

    const int tid = threadIdx.x;
    const int n0 = blockIdx.x * 128;

    if (tid < 128) {
        int n = n0 + tid; if (n >= N) n = N - 1;
        rb[tid] = batch[n];
    }

    float acc[8][8];
#pragma unroll
    for (int i = 0; i < 8; ++i)
#pragma unroll
        for (int j = 0; j < 8; ++j) acc[i][j] = 0.0f;

    const int ar = tid >> 1;
    const int ac = (tid & 1) * 16;
    const int br = tid >> 3;
    const int bc = (tid & 7) * 16;
    const int ty = tid >> 4;
    const int tx = tid & 15;

    int arow = n0 + ar; if (arow >= N) arow = N - 1;

    float bias_r[8];
#pragma unroll
    for (int j = 0; j < 8; ++j) bias_r[j] = bias[tx * 8 + j];

    __syncthreads();

    for (int c = 0; c < 12; ++c) {
        const int k0 = c * 32;
        const float* abase;
        if (k0 < 128)       abase = node + (size_t)arow * D + k0;
        else if (k0 < 256)  abase = ebar + (size_t)arow * D + (k0 - 128);
        else                abase = u    + (size_t)rb[ar] * D + (k0 - 256);
        float4 av[4];
#pragma unroll
        for (int i = 0; i < 4; ++i) av[i] = *(const float4*)(abase + ac + 4 * i);
        const float* wbase = W + (size_t)(k0 + br) * D + bc;
        float4 bv[4];
#pragma unroll
        for (int i = 0; i < 4; ++i) bv[i] = *(const float4*)(wbase + 4 * i);

        __syncthreads();
#pragma unroll
        for (int i = 0; i < 4; ++i) *(float4*)&As[ar][ac + 4 * i] = av[i];
#pragma unroll
        for (int i = 0; i < 4; ++i) *(float4*)&Bs[br][bc + 4 * i] = bv[i];
        __syncthreads();

#pragma unroll
        for (int kk = 0; kk < 32; kk += 4) {
            float4 a4[8];
#pragma unroll
            for (int i = 0; i < 8; ++i) a4[i] = *(const float4*)&As[ty * 8 + i][kk];
#pragma unroll
            for (int q = 0; q < 4; ++q) {
                float4 b0 = *(const float4*)&Bs[kk + q][tx * 8];
                float4 b1 = *(const float4*)&Bs[kk + q][tx * 8 + 4];
                float bj[8] = {b0.x, b0.y, b0.z, b0.w, b1.x, b1.y, b1.z, b1.w};
#pragma unroll
                for (int i = 0; i < 8; ++i) {
                    float a = (q == 0) ? a4[i].x : (q == 1) ? a4[i].y : (q == 2) ? a4[i].z : a4[i].w;
#pragma unroll
                    for (int j = 0; j < 8; ++j) acc[i][j] += a * bj[j];
                }
            }
        }
    }

#pragma unroll
    for (int i = 0; i < 8; ++i) {
        int n = n0 + ty * 8 + i;
        if (n < N) {
            float v[8];
#pragma unroll
            for (int j = 0; j < 8; ++j) v[j] = fmaxf(acc[i][j] + bias_r[j], 0.0f);
            float* nrow = node + (size_t)n * D + tx * 8;
            *(float4*)(nrow)     = make_float4(v[0], v[1], v[2], v[3]);
            *(float4*)(nrow + 4) = make_float4(v[4], v[5], v[6], v[7]);
        }
    }
}

// ---------------------------------------------------------------- per-graph means (batch sorted -> range reduce)
__global__ void reduce_kernel(
    const float* __restrict__ node, const float* __restrict__ ebar,
    const int* __restrict__ batch,
    float* __restrict__ nmean, float* __restrict__ emean, int N)
{
    const int g = blockIdx.x;
    const int j = threadIdx.x;   // 0..127
    int lo = lower_bound_i(batch, N, g);
    int hi = lower_bound_i(batch, N, g + 1);
    float sn = 0.0f, se = 0.0f;
    for (int n = lo; n < hi; ++n) {
        sn += node[(size_t)n * D + j];
        se += ebar[(size_t)n * D + j];
    }
    float inv = 1.0f / (float)max(hi - lo, 1);
    nmean[g * D + j] = sn * inv;
    emean[g * D + j] = se * inv;
}

// ---------------------------------------------------------------- global update: u = relu([nmean,emean,u] @ Wg + b)
__global__ void global_kernel(
    const float* __restrict__ nmean, const float* __restrict__ emean,
    float* __restrict__ u,
    const float* __restrict__ W, const float* __restrict__ bias)
{
    __shared__ float gin[384];
    const int g = blockIdx.x;
    const int j = threadIdx.x;   // 0..127
    gin[j]       = nmean[g * D + j];
    gin[128 + j] = emean[g * D + j];
    gin[256 + j] = u[g * D + j];
    __syncthreads();
    float s = bias[j];
    for (int k = 0; k < 384; ++k) s += gin[k] * W[(size_t)k * D + j];
    u[g * D + j] = fmaxf(s, 0.0f);
}

// ---------------------------------------------------------------- readout: out[g] = [nmean,emean,u[g]] @ lin_w + lin_b
__global__ void out_kernel(
    const float* __restrict__ nmean, const float* __restrict__ emean,
    const float* __restrict__ u, const int* __restrict__ batch,
    const float* __restrict__ lw, const float* __restrict__ lb,
    float* __restrict__ out, int N, int NC)
{
    __shared__ float pin[384];
    __shared__ int cntg;
    const int g = blockIdx.x;
    const int t = threadIdx.x;   // 0..383
    if (t == 0) {
        int lo = lower_bound_i(batch, N, g);
        int hi = lower_bound_i(batch, N, g + 1);
        cntg = hi - lo;
    }
    __syncthreads();
    if (t < 128)       pin[t] = nmean[g * D + t];
    else if (t < 256)  pin[t] = emean[g * D + (t - 128)];
    else               pin[t] = (cntg > 0) ? u[g * D + (t - 256)] : 0.0f;
    __syncthreads();
    int c = t >> 5, w = t & 31;
    if (c < NC) {
        float s = 0.0f;
        for (int k = w; k < 384; k += 32) s += pin[k] * lw[(size_t)k * NC + c];
#pragma unroll
        for (int off = 16; off > 0; off >>= 1) s += __shfl_down(s, off, 32);
        if (w == 0) out[g * NC + c] = s + lb[c];
    }
}

// ---------------------------------------------------------------- driver
extern "C" void kernel_launch(void* const* d_in, const int* in_sizes, int n_in,
                              void* d_out, int out_size, void* d_ws, size_t ws_size,
                              hipStream_t stream) {
    float* node = (float*)d_in[0];
    float* edge = (float*)d_in[1];
    float* u    = (float*)d_in[2];
    const int* eidx  = (const int*)d_in[3];
    const int* batch = (const int*)d_in[4];
    const float* We_w = (const float*)d_in[5];
    const float* We_b = (const float*)d_in[6];
    const float* Wn_w = (const float*)d_in[7];
    const float* Wn_b = (const float*)d_in[8];
    const float* Wg_w = (const float*)d_in[9];
    const float* Wg_b = (const float*)d_in[10];
    const float* lin_w = (const float*)d_in[11];
    const float* lin_b = (const float*)d_in[12];

    const int N = in_sizes[0] / D;        // 50000
    const int E = in_sizes[3] / 2;        // 600000
    const int G = in_sizes[2] / D;        // 64
    const int NC = out_size / G;          // 10
    const int* src = eidx;
    const int* dst = eidx + E;

    float* ws = (float*)d_ws;
    float* ebar  = ws;                               // N*D
    float* cnt   = ebar + (size_t)N * D;             // N
    float* nmean = cnt + N;                          // G*D
    float* emean = nmean + (size_t)G * D;            // G*D

    // in-degree counts (dst fixed across passes)
    hipMemsetAsync(cnt, 0, (size_t)N * sizeof(float), stream);
    count_kernel<<<(E + 255) / 256, 256, 0, stream>>>(dst, cnt, E);

    const int edge_blocks = (E + 127) / 128;
    const int node_blocks = (N + 127) / 128;
    const int n4 = N * D / 4;

    for (int pass = 0; pass < 3; ++pass) {
        hipMemsetAsync(ebar, 0, (size_t)N * D * sizeof(float), stream);
        edge_gemm<<<edge_blocks, 256, 0, stream>>>(node, edge, u, src, dst, batch,
                                                   We_w, We_b, ebar, E);
        norm_kernel<<<(n4 + 255) / 256, 256, 0, stream>>>(ebar, cnt, n4);
        node_gemm<<<node_blocks, 256, 0, stream>>>(node, ebar, u, batch, Wn_w, Wn_b, N);
        reduce_kernel<<<G, 128, 0, stream>>>(node, ebar, batch, nmean, emean, N);
        global_kernel<<<G, 128, 0, stream>>>(nmean, emean, u, Wg_w, Wg_b);
    }
    out_kernel<<<G, 384, 0, stream>>>(nmean, emean, u, batch, lin_w, lin_b,
                                      (float*)d_out, N, NC);
}

// Round 2
// 2062.067 us; speedup vs baseline: 4.5957x; 4.5957x over previous
//
#include <hip/hip_runtime.h>
#include <math.h>

#define D 128

typedef short bf16x8 __attribute__((ext_vector_type(8)));
typedef float f32x4 __attribute__((ext_vector_type(4)));

// ---------------------------------------------------------------- bf16 helpers (RNE)
__device__ __forceinline__ ushort f2b(float f) {
    union { float f; unsigned u; } v; v.f = f;
    unsigned r = v.u + 0x7FFFu + ((v.u >> 16) & 1u);
    return (ushort)(r >> 16);
}
__device__ __forceinline__ float b2f(ushort b) {
    union { unsigned u; float f; } v; v.u = ((unsigned)b) << 16;
    return v.f;
}
// async global->LDS, 16B per lane; LDS dest = wave-uniform base + lane*16
__device__ __forceinline__ void gl_lds16(const void* g, void* l) {
    __builtin_amdgcn_global_load_lds(
        (const __attribute__((address_space(1))) void*)g,
        (__attribute__((address_space(3))) void*)l, 16, 0, 0);
}
__device__ __forceinline__ int lower_bound_i(const int* __restrict__ a, int n, int v) {
    int lo = 0, hi = n;
    while (lo < hi) { int m = (lo + hi) >> 1; if (a[m] < v) lo = m + 1; else hi = m; }
    return lo;
}

// ---------------------------------------------------------------- CSR build (dst fixed per call)
__global__ void count_kernel(const int* __restrict__ dst, int* __restrict__ cnt, int E) {
    int e = blockIdx.x * blockDim.x + threadIdx.x;
    if (e < E) atomicAdd(&cnt[dst[e]], 1);
}

__global__ void scan_kernel(const int* __restrict__ cnt, int* __restrict__ offs, int N) {
    __shared__ int part[1024];
    const int t = threadIdx.x;
    const int chunk = (N + 1023) >> 10;
    int lo = t * chunk; if (lo > N) lo = N;
    int hi = lo + chunk; if (hi > N) hi = N;
    int s = 0;
    for (int i = lo; i < hi; ++i) s += cnt[i];
    part[t] = s;
    __syncthreads();
    if (t == 0) {
        int a = 0;
        for (int i = 0; i < 1024; ++i) { int v = part[i]; part[i] = a; a += v; }
        offs[N] = a;
    }
    __syncthreads();
    int a = part[t];
    for (int i = lo; i < hi; ++i) { offs[i] = a; a += cnt[i]; }
}

__global__ void scatter_kernel(const int* __restrict__ dst, const int* __restrict__ offs,
                               int* __restrict__ fill, int* __restrict__ csr, int E) {
    int e = blockIdx.x * blockDim.x + threadIdx.x;
    if (e < E) {
        int d = dst[e];
        int p = offs[d] + atomicAdd(&fill[d], 1);
        csr[p] = e;
    }
}

// ---------------------------------------------------------------- conversions
__global__ void f2b_kernel(const float* __restrict__ in, ushort* __restrict__ out, int n) {
    int i = blockIdx.x * blockDim.x + threadIdx.x;
    if (i < n) out[i] = f2b(in[i]);
}

// edge fp32 [E][128] -> bf16 in-place: row e's 128 bf16 stored in first 256B of its
// 512B slot (row stride stays 256 ushorts). One row = 32 consecutive lanes of one
// wave; reads issue before writes in program order -> race-free.
__global__ void conv_edge_kernel(float* __restrict__ edge, int E) {
    int gid = blockIdx.x * blockDim.x + threadIdx.x;  // one per 4 elements
    if (gid < E * 32) {
        int row = gid >> 5, q = gid & 31;
        float4 v = *(const float4*)(edge + (size_t)row * D + q * 4);
        ushort4 o;
        o.x = f2b(v.x); o.y = f2b(v.y); o.z = f2b(v.z); o.w = f2b(v.w);
        *(ushort4*)((ushort*)edge + (size_t)row * 256 + q * 4) = o;
    }
}

// W[K][128] fp32 -> Wt[128][K] bf16
__global__ void transpose_w(const float* __restrict__ W, ushort* __restrict__ Wt, int K) {
    int i = blockIdx.x * blockDim.x + threadIdx.x;
    if (i < K * D) { int k = i >> 7, n = i & 127; Wt[(size_t)n * K + k] = f2b(W[i]); }
}

// ---------------------------------------------------------------- edge update GEMM (MFMA bf16)
// tile 128 edges x 128 cols, K=512 (4 sources x 128). m97 structure.
__global__ __launch_bounds__(256) void edge_gemm(
    const ushort* __restrict__ node_bf, ushort* __restrict__ edge_u,
    const ushort* __restrict__ u_bf,
    const int* __restrict__ src, const int* __restrict__ dst,
    const int* __restrict__ batch,
    const ushort* __restrict__ Wt, const float* __restrict__ bias, int E)
{
    __shared__ ushort As[128 * 32];   // [row][32k] contiguous (global_load_lds layout)
    __shared__ ushort Bs[128 * 32];   // [n][32k]
    __shared__ int rs[128], rd[128], rb[128];

    const int tid = threadIdx.x;
    const int w = tid >> 6, l = tid & 63;
    const int e0 = blockIdx.x * 128;

    if (tid < 128) {
        int e = e0 + tid; if (e >= E) e = E - 1;
        int s = src[e];
        rs[tid] = s; rd[tid] = dst[e]; rb[tid] = batch[s];
    }

    f32x4 acc[4][4];
#pragma unroll
    for (int i = 0; i < 4; ++i)
#pragma unroll
        for (int j = 0; j < 4; ++j) acc[i][j] = (f32x4)0.0f;

    const int wm = (w >> 1) * 64, wn = (w & 1) * 64;
    float bj4[4];
#pragma unroll
    for (int j = 0; j < 4; ++j) bj4[j] = bias[wn + j * 16 + (l & 15)];

    const int srow = l >> 2;           // 0..15 within seg
    const int part = (l & 3) * 8;      // ushort offset within 64B row chunk

    __syncthreads();                   // rs/rd/rb visible

    for (int c = 0; c < 16; ++c) {
        const int srcsel = c >> 2;
        const int kl = (c & 3) * 32;   // k offset within source row (ushorts)

#pragma unroll
        for (int t = 0; t < 2; ++t) {  // A: 2 segs of 16 rows per wave
            const int s = w + t * 4;
            const int row = s * 16 + srow;
            const ushort* gp;
            if (srcsel == 0)      gp = node_bf + (size_t)rs[row] * D + kl + part;
            else if (srcsel == 1) gp = node_bf + (size_t)rd[row] * D + kl + part;
            else if (srcsel == 2) { int e = e0 + row; if (e >= E) e = E - 1;
                                    gp = edge_u + (size_t)e * 256 + kl + part; }
            else                  gp = u_bf + (size_t)rb[row] * D + kl + part;
            gl_lds16(gp, &As[s * 512]);
        }
#pragma unroll
        for (int t = 0; t < 2; ++t) {  // B: 2 segs of 16 cols per wave
            const int s = w + t * 4;
            const int n = s * 16 + srow;
            gl_lds16(Wt + (size_t)n * 512 + c * 32 + part, &Bs[s * 512]);
        }
        __syncthreads();               // drains vmcnt -> LDS ready

        bf16x8 af[4], bfr[4];
#pragma unroll
        for (int i = 0; i < 4; ++i)
            af[i] = *(const bf16x8*)&As[(wm + i * 16 + (l & 15)) * 32 + (l >> 4) * 8];
#pragma unroll
        for (int j = 0; j < 4; ++j)
            bfr[j] = *(const bf16x8*)&Bs[(wn + j * 16 + (l & 15)) * 32 + (l >> 4) * 8];
#pragma unroll
        for (int i = 0; i < 4; ++i)
#pragma unroll
            for (int j = 0; j < 4; ++j)
                acc[i][j] = __builtin_amdgcn_mfma_f32_16x16x32_bf16(af[i], bfr[j], acc[i][j], 0, 0, 0);
        __syncthreads();               // compute done before next overwrite
    }

    // epilogue: +bias, relu, bf16 store (C layout: col=lane&15, row=quad*4+r)
#pragma unroll
    for (int i = 0; i < 4; ++i) {
#pragma unroll
        for (int r = 0; r < 4; ++r) {
            const int m = wm + i * 16 + (l >> 4) * 4 + r;
            const int e = e0 + m;
            if (e < E) {
                ushort* ep = edge_u + (size_t)e * 256;
#pragma unroll
                for (int j = 0; j < 4; ++j) {
                    float v = fmaxf(acc[i][j][r] + bj4[j], 0.0f);
                    ep[wn + j * 16 + (l & 15)] = f2b(v);
                }
            }
        }
    }
}

// ---------------------------------------------------------------- ebar gather (replaces atomics)
__global__ void gather_ebar(const ushort* __restrict__ edge_u, const int* __restrict__ offs,
                            const int* __restrict__ csr, ushort* __restrict__ ebar_bf, int N)
{
    int n = blockIdx.x * 2 + (threadIdx.x >> 7);
    int col = threadIdx.x & 127;
    if (n >= N) return;
    int lo = offs[n], hi = offs[n + 1];
    float s = 0.0f;
    for (int j = lo; j < hi; ++j) {
        int e = csr[j];
        s += b2f(edge_u[(size_t)e * 256 + col]);
    }
    ebar_bf[(size_t)n * D + col] = f2b(s / (float)max(hi - lo, 1));
}

// ---------------------------------------------------------------- node update GEMM (MFMA bf16), K=384
__global__ __launch_bounds__(256) void node_gemm(
    ushort* __restrict__ node_bf, const ushort* __restrict__ ebar_bf,
    const ushort* __restrict__ u_bf, const int* __restrict__ batch,
    const ushort* __restrict__ Wt, const float* __restrict__ bias, int N)
{
    __shared__ ushort As[128 * 32];
    __shared__ ushort Bs[128 * 32];
    __shared__ int rb[128];

    const int tid = threadIdx.x;
    const int w = tid >> 6, l = tid & 63;
    const int n0 = blockIdx.x * 128;

    if (tid < 128) {
        int n = n0 + tid; if (n >= N) n = N - 1;
        rb[tid] = batch[n];
    }

    f32x4 acc[4][4];
#pragma unroll
    for (int i = 0; i < 4; ++i)
#pragma unroll
        for (int j = 0; j < 4; ++j) acc[i][j] = (f32x4)0.0f;

    const int wm = (w >> 1) * 64, wn = (w & 1) * 64;
    float bj4[4];
#pragma unroll
    for (int j = 0; j < 4; ++j) bj4[j] = bias[wn + j * 16 + (l & 15)];

    const int srow = l >> 2;
    const int part = (l & 3) * 8;

    __syncthreads();

    for (int c = 0; c < 12; ++c) {
        const int srcsel = c >> 2;
        const int kl = (c & 3) * 32;

#pragma unroll
        for (int t = 0; t < 2; ++t) {
            const int s = w + t * 4;
            const int row = s * 16 + srow;
            int n = n0 + row; if (n >= N) n = N - 1;
            const ushort* gp;
            if (srcsel == 0)      gp = node_bf + (size_t)n * D + kl + part;
            else if (srcsel == 1) gp = ebar_bf + (size_t)n * D + kl + part;
            else                  gp = u_bf + (size_t)rb[row] * D + kl + part;
            gl_lds16(gp, &As[s * 512]);
        }
#pragma unroll
        for (int t = 0; t < 2; ++t) {
            const int s = w + t * 4;
            const int n = s * 16 + srow;
            gl_lds16(Wt + (size_t)n * 384 + c * 32 + part, &Bs[s * 512]);
        }
        __syncthreads();

        bf16x8 af[4], bfr[4];
#pragma unroll
        for (int i = 0; i < 4; ++i)
            af[i] = *(const bf16x8*)&As[(wm + i * 16 + (l & 15)) * 32 + (l >> 4) * 8];
#pragma unroll
        for (int j = 0; j < 4; ++j)
            bfr[j] = *(const bf16x8*)&Bs[(wn + j * 16 + (l & 15)) * 32 + (l >> 4) * 8];
#pragma unroll
        for (int i = 0; i < 4; ++i)
#pragma unroll
            for (int j = 0; j < 4; ++j)
                acc[i][j] = __builtin_amdgcn_mfma_f32_16x16x32_bf16(af[i], bfr[j], acc[i][j], 0, 0, 0);
        __syncthreads();
    }

#pragma unroll
    for (int i = 0; i < 4; ++i) {
#pragma unroll
        for (int r = 0; r < 4; ++r) {
            const int m = wm + i * 16 + (l >> 4) * 4 + r;
            const int n = n0 + m;
            if (n < N) {
#pragma unroll
                for (int j = 0; j < 4; ++j) {
                    float v = fmaxf(acc[i][j][r] + bj4[j], 0.0f);
                    node_bf[(size_t)n * D + wn + j * 16 + (l & 15)] = f2b(v);
                }
            }
        }
    }
}

// ---------------------------------------------------------------- per-graph means (batch sorted)
__global__ void reduce_kernel(
    const ushort* __restrict__ node_bf, const ushort* __restrict__ ebar_bf,
    const int* __restrict__ batch,
    float* __restrict__ nmean, float* __restrict__ emean, int N)
{
    const int g = blockIdx.x;
    const int j = threadIdx.x;   // 0..127
    int lo = lower_bound_i(batch, N, g);
    int hi = lower_bound_i(batch, N, g + 1);
    float sn = 0.0f, se = 0.0f;
    for (int n = lo; n < hi; ++n) {
        sn += b2f(node_bf[(size_t)n * D + j]);
        se += b2f(ebar_bf[(size_t)n * D + j]);
    }
    float inv = 1.0f / (float)max(hi - lo, 1);
    nmean[g * D + j] = sn * inv;
    emean[g * D + j] = se * inv;
}

// ---------------------------------------------------------------- global update (fp32, tiny)
__global__ void global_kernel(
    const float* __restrict__ nmean, const float* __restrict__ emean,
    float* __restrict__ u,
    const float* __restrict__ W, const float* __restrict__ bias)
{
    __shared__ float gin[384];
    const int g = blockIdx.x;
    const int j = threadIdx.x;   // 0..127
    gin[j]       = nmean[g * D + j];
    gin[128 + j] = emean[g * D + j];
    gin[256 + j] = u[g * D + j];
    __syncthreads();
    float s = bias[j];
    for (int k = 0; k < 384; ++k) s += gin[k] * W[(size_t)k * D + j];
    u[g * D + j] = fmaxf(s, 0.0f);
}

// ---------------------------------------------------------------- readout
__global__ void out_kernel(
    const float* __restrict__ nmean, const float* __restrict__ emean,
    const float* __restrict__ u, const int* __restrict__ batch,
    const float* __restrict__ lw, const float* __restrict__ lb,
    float* __restrict__ out, int N, int NC)
{
    __shared__ float pin[384];
    __shared__ int cntg;
    const int g = blockIdx.x;
    const int t = threadIdx.x;   // 0..383
    if (t == 0) {
        int lo = lower_bound_i(batch, N, g);
        int hi = lower_bound_i(batch, N, g + 1);
        cntg = hi - lo;
    }
    __syncthreads();
    if (t < 128)       pin[t] = nmean[g * D + t];
    else if (t < 256)  pin[t] = emean[g * D + (t - 128)];
    else               pin[t] = (cntg > 0) ? u[g * D + (t - 256)] : 0.0f;
    __syncthreads();
    int c = t >> 5, wv = t & 31;
    if (c < NC) {
        float s = 0.0f;
        for (int k = wv; k < 384; k += 32) s += pin[k] * lw[(size_t)k * NC + c];
#pragma unroll
        for (int off = 16; off > 0; off >>= 1) s += __shfl_down(s, off, 32);
        if (wv == 0) out[g * NC + c] = s + lb[c];
    }
}

// ---------------------------------------------------------------- driver
extern "C" void kernel_launch(void* const* d_in, const int* in_sizes, int n_in,
                              void* d_out, int out_size, void* d_ws, size_t ws_size,
                              hipStream_t stream) {
    float* node = (float*)d_in[0];
    float* edge = (float*)d_in[1];
    float* u    = (float*)d_in[2];
    const int* eidx  = (const int*)d_in[3];
    const int* batch = (const int*)d_in[4];
    const float* We_w = (const float*)d_in[5];
    const float* We_b = (const float*)d_in[6];
    const float* Wn_w = (const float*)d_in[7];
    const float* Wn_b = (const float*)d_in[8];
    const float* Wg_w = (const float*)d_in[9];
    const float* Wg_b = (const float*)d_in[10];
    const float* lin_w = (const float*)d_in[11];
    const float* lin_b = (const float*)d_in[12];

    const int N = in_sizes[0] / D;        // 50000
    const int E = in_sizes[3] / 2;        // 600000
    const int G = in_sizes[2] / D;        // 64
    const int NC = out_size / G;          // 10
    const int* src = eidx;
    const int* dst = eidx + E;

    // workspace carve-up (256B-aligned chunks)
    char* p = (char*)d_ws;
    auto carve = [&](size_t bytes) { void* r = p; p += (bytes + 255) & ~(size_t)255; return r; };
    ushort* node_bf = (ushort*)carve((size_t)N * D * 2);
    ushort* ebar_bf = (ushort*)carve((size_t)N * D * 2);
    ushort* u_bf    = (ushort*)carve((size_t)G * D * 2);
    ushort* Wet     = (ushort*)carve((size_t)512 * D * 2);
    ushort* Wnt     = (ushort*)carve((size_t)384 * D * 2);
    int*    cnt     = (int*)carve((size_t)N * 4);
    int*    offs    = (int*)carve((size_t)(N + 1) * 4);
    int*    fill    = (int*)carve((size_t)N * 4);
    int*    csr     = (int*)carve((size_t)E * 4);
    float*  nmean   = (float*)carve((size_t)G * D * 4);
    float*  emean   = (float*)carve((size_t)G * D * 4);

    ushort* edge_u = (ushort*)edge;  // bf16-in-place, row stride 256 ushorts

    // CSR build (once per call; ws is re-poisoned each call)
    hipMemsetAsync(cnt, 0, (size_t)N * 4, stream);
    hipMemsetAsync(fill, 0, (size_t)N * 4, stream);
    count_kernel<<<(E + 255) / 256, 256, 0, stream>>>(dst, cnt, E);
    scan_kernel<<<1, 1024, 0, stream>>>(cnt, offs, N);
    scatter_kernel<<<(E + 255) / 256, 256, 0, stream>>>(dst, offs, fill, csr, E);

    // bf16 conversions / weight transposes
    f2b_kernel<<<(N * D + 255) / 256, 256, 0, stream>>>(node, node_bf, N * D);
    f2b_kernel<<<(G * D + 255) / 256, 256, 0, stream>>>(u, u_bf, G * D);
    transpose_w<<<(512 * D + 255) / 256, 256, 0, stream>>>(We_w, Wet, 512);
    transpose_w<<<(384 * D + 255) / 256, 256, 0, stream>>>(Wn_w, Wnt, 384);
    conv_edge_kernel<<<(E * 32 + 255) / 256, 256, 0, stream>>>(edge, E);

    const int edge_blocks = (E + 127) / 128;
    const int node_blocks = (N + 127) / 128;

    for (int pass = 0; pass < 3; ++pass) {
        edge_gemm<<<edge_blocks, 256, 0, stream>>>(node_bf, edge_u, u_bf, src, dst, batch,
                                                   Wet, We_b, E);
        gather_ebar<<<(N + 1) / 2, 256, 0, stream>>>(edge_u, offs, csr, ebar_bf, N);
        node_gemm<<<node_blocks, 256, 0, stream>>>(node_bf, ebar_bf, u_bf, batch,
                                                   Wnt, Wn_b, N);
        reduce_kernel<<<G, 128, 0, stream>>>(node_bf, ebar_bf, batch, nmean, emean, N);
        global_kernel<<<G, 128, 0, stream>>>(nmean, emean, u, Wg_w, Wg_b);
        f2b_kernel<<<(G * D + 255) / 256, 256, 0, stream>>>(u, u_bf, G * D);
    }
    out_kernel<<<G, 384, 0, stream>>>(nmean, emean, u, batch, lin_w, lin_b,
                                      (float*)d_out, N, NC);
}

// Round 3
// 1505.400 us; speedup vs baseline: 6.2951x; 1.3698x over previous
//
#include <hip/hip_runtime.h>
#include <math.h>

#define D 128

typedef short bf16x8 __attribute__((ext_vector_type(8)));
typedef float f32x4 __attribute__((ext_vector_type(4)));

// ---------------------------------------------------------------- bf16 helpers (RNE)
__device__ __forceinline__ ushort f2b(float f) {
    union { float f; unsigned u; } v; v.f = f;
    unsigned r = v.u + 0x7FFFu + ((v.u >> 16) & 1u);
    return (ushort)(r >> 16);
}
__device__ __forceinline__ float b2f(ushort b) {
    union { unsigned u; float f; } v; v.u = ((unsigned)b) << 16;
    return v.f;
}
// async global->LDS, 16B per lane; LDS dest = wave-uniform base + lane*16
__device__ __forceinline__ void gl_lds16(const void* g, void* l) {
    __builtin_amdgcn_global_load_lds(
        (const __attribute__((address_space(1))) void*)g,
        (__attribute__((address_space(3))) void*)l, 16, 0, 0);
}
__device__ __forceinline__ int lower_bound_i(const int* __restrict__ a, int n, int v) {
    int lo = 0, hi = n;
    while (lo < hi) { int m = (lo + hi) >> 1; if (a[m] < v) lo = m + 1; else hi = m; }
    return lo;
}

// ---------------------------------------------------------------- CSR build (dst fixed per call)
__global__ void count_kernel(const int* __restrict__ dst, int* __restrict__ cnt, int E) {
    int e = blockIdx.x * blockDim.x + threadIdx.x;
    if (e < E) atomicAdd(&cnt[dst[e]], 1);
}

__global__ void scan_kernel(const int* __restrict__ cnt, int* __restrict__ offs, int N) {
    __shared__ int part[1024];
    const int t = threadIdx.x;
    const int chunk = (N + 1023) >> 10;
    int lo = t * chunk; if (lo > N) lo = N;
    int hi = lo + chunk; if (hi > N) hi = N;
    int s = 0;
    for (int i = lo; i < hi; ++i) s += cnt[i];
    part[t] = s;
    __syncthreads();
    if (t == 0) {
        int a = 0;
        for (int i = 0; i < 1024; ++i) { int v = part[i]; part[i] = a; a += v; }
        offs[N] = a;
    }
    __syncthreads();
    int a = part[t];
    for (int i = lo; i < hi; ++i) { offs[i] = a; a += cnt[i]; }
}

__global__ void scatter_kernel(const int* __restrict__ dst, const int* __restrict__ offs,
                               int* __restrict__ fill, int* __restrict__ csr, int E) {
    int e = blockIdx.x * blockDim.x + threadIdx.x;
    if (e < E) {
        int d = dst[e];
        int p = offs[d] + atomicAdd(&fill[d], 1);
        csr[p] = e;
    }
}

// ---------------------------------------------------------------- conversions
__global__ void f2b_kernel(const float* __restrict__ in, ushort* __restrict__ out, int n) {
    int i = blockIdx.x * blockDim.x + threadIdx.x;
    if (i < n) out[i] = f2b(in[i]);
}

// edge fp32 [E][128] -> bf16 in-place: row e's 128 bf16 stored in first 256B of its
// 512B slot (row stride stays 256 ushorts). One row = 32 consecutive lanes of one
// wave; reads issue before writes in program order -> race-free.
__global__ void conv_edge_kernel(float* __restrict__ edge, int E) {
    int gid = blockIdx.x * blockDim.x + threadIdx.x;  // one per 4 elements
    if (gid < E * 32) {
        int row = gid >> 5, q = gid & 31;
        float4 v = *(const float4*)(edge + (size_t)row * D + q * 4);
        ushort4 o;
        o.x = f2b(v.x); o.y = f2b(v.y); o.z = f2b(v.z); o.w = f2b(v.w);
        *(ushort4*)((ushort*)edge + (size_t)row * 256 + q * 4) = o;
    }
}

// W[K][128] fp32 -> Wt[128][K] bf16
__global__ void transpose_w(const float* __restrict__ W, ushort* __restrict__ Wt, int K) {
    int i = blockIdx.x * blockDim.x + threadIdx.x;
    if (i < K * D) { int k = i >> 7, n = i & 127; Wt[(size_t)n * K + k] = f2b(W[i]); }
}

// ---------------------------------------------------------------- edge update GEMM (MFMA bf16)
// tile 128 edges x 128 cols, K=512 (4 sources x 128). m97 structure.
__global__ __launch_bounds__(256) void edge_gemm(
    const ushort* __restrict__ node_bf, ushort* __restrict__ edge_u,
    const ushort* __restrict__ u_bf,
    const int* __restrict__ src, const int* __restrict__ dst,
    const int* __restrict__ batch,
    const ushort* __restrict__ Wt, const float* __restrict__ bias, int E)
{
    __shared__ ushort As[128 * 32];   // [row][32k] contiguous (global_load_lds layout)
    __shared__ ushort Bs[128 * 32];   // [n][32k]
    __shared__ int rs[128], rd[128], rb[128];

    const int tid = threadIdx.x;
    const int w = tid >> 6, l = tid & 63;
    const int e0 = blockIdx.x * 128;

    if (tid < 128) {
        int e = e0 + tid; if (e >= E) e = E - 1;
        int s = src[e];
        rs[tid] = s; rd[tid] = dst[e]; rb[tid] = batch[s];
    }

    f32x4 acc[4][4];
#pragma unroll
    for (int i = 0; i < 4; ++i)
#pragma unroll
        for (int j = 0; j < 4; ++j) acc[i][j] = (f32x4)0.0f;

    const int wm = (w >> 1) * 64, wn = (w & 1) * 64;
    float bj4[4];
#pragma unroll
    for (int j = 0; j < 4; ++j) bj4[j] = bias[wn + j * 16 + (l & 15)];

    const int srow = l >> 2;           // 0..15 within seg
    const int part = (l & 3) * 8;      // ushort offset within 64B row chunk

    __syncthreads();                   // rs/rd/rb visible

    for (int c = 0; c < 16; ++c) {
        const int srcsel = c >> 2;
        const int kl = (c & 3) * 32;   // k offset within source row (ushorts)

#pragma unroll
        for (int t = 0; t < 2; ++t) {  // A: 2 segs of 16 rows per wave
            const int s = w + t * 4;
            const int row = s * 16 + srow;
            const ushort* gp;
            if (srcsel == 0)      gp = node_bf + (size_t)rs[row] * D + kl + part;
            else if (srcsel == 1) gp = node_bf + (size_t)rd[row] * D + kl + part;
            else if (srcsel == 2) { int e = e0 + row; if (e >= E) e = E - 1;
                                    gp = edge_u + (size_t)e * 256 + kl + part; }
            else                  gp = u_bf + (size_t)rb[row] * D + kl + part;
            gl_lds16(gp, &As[s * 512]);
        }
#pragma unroll
        for (int t = 0; t < 2; ++t) {  // B: 2 segs of 16 cols per wave
            const int s = w + t * 4;
            const int n = s * 16 + srow;
            gl_lds16(Wt + (size_t)n * 512 + c * 32 + part, &Bs[s * 512]);
        }
        __syncthreads();               // drains vmcnt -> LDS ready

        bf16x8 af[4], bfr[4];
#pragma unroll
        for (int i = 0; i < 4; ++i)
            af[i] = *(const bf16x8*)&As[(wm + i * 16 + (l & 15)) * 32 + (l >> 4) * 8];
#pragma unroll
        for (int j = 0; j < 4; ++j)
            bfr[j] = *(const bf16x8*)&Bs[(wn + j * 16 + (l & 15)) * 32 + (l >> 4) * 8];
#pragma unroll
        for (int i = 0; i < 4; ++i)
#pragma unroll
            for (int j = 0; j < 4; ++j)
                acc[i][j] = __builtin_amdgcn_mfma_f32_16x16x32_bf16(af[i], bfr[j], acc[i][j], 0, 0, 0);
        __syncthreads();               // compute done before next overwrite
    }

    // epilogue: +bias, relu, bf16 store (C layout: col=lane&15, row=quad*4+r)
#pragma unroll
    for (int i = 0; i < 4; ++i) {
#pragma unroll
        for (int r = 0; r < 4; ++r) {
            const int m = wm + i * 16 + (l >> 4) * 4 + r;
            const int e = e0 + m;
            if (e < E) {
                ushort* ep = edge_u + (size_t)e * 256;
#pragma unroll
                for (int j = 0; j < 4; ++j) {
                    float v = fmaxf(acc[i][j][r] + bj4[j], 0.0f);
                    ep[wn + j * 16 + (l & 15)] = f2b(v);
                }
            }
        }
    }
}

// ---------------------------------------------------------------- ebar gather (CSR, no atomics)
__global__ void gather_ebar(const ushort* __restrict__ edge_u, const int* __restrict__ offs,
                            const int* __restrict__ csr, ushort* __restrict__ ebar_bf, int N)
{
    int n = blockIdx.x * 2 + (threadIdx.x >> 7);
    int col = threadIdx.x & 127;
    if (n >= N) return;
    int lo = offs[n], hi = offs[n + 1];
    float s = 0.0f;
    for (int j = lo; j < hi; ++j) {
        int e = csr[j];
        s += b2f(edge_u[(size_t)e * 256 + col]);
    }
    ebar_bf[(size_t)n * D + col] = f2b(s / (float)max(hi - lo, 1));
}

// ---------------------------------------------------------------- node update GEMM (MFMA bf16), K=384
__global__ __launch_bounds__(256) void node_gemm(
    ushort* __restrict__ node_bf, const ushort* __restrict__ ebar_bf,
    const ushort* __restrict__ u_bf, const int* __restrict__ batch,
    const ushort* __restrict__ Wt, const float* __restrict__ bias, int N)
{
    __shared__ ushort As[128 * 32];
    __shared__ ushort Bs[128 * 32];
    __shared__ int rb[128];

    const int tid = threadIdx.x;
    const int w = tid >> 6, l = tid & 63;
    const int n0 = blockIdx.x * 128;

    if (tid < 128) {
        int n = n0 + tid; if (n >= N) n = N - 1;
        rb[tid] = batch[n];
    }

    f32x4 acc[4][4];
#pragma unroll
    for (int i = 0; i < 4; ++i)
#pragma unroll
        for (int j = 0; j < 4; ++j) acc[i][j] = (f32x4)0.0f;

    const int wm = (w >> 1) * 64, wn = (w & 1) * 64;
    float bj4[4];
#pragma unroll
    for (int j = 0; j < 4; ++j) bj4[j] = bias[wn + j * 16 + (l & 15)];

    const int srow = l >> 2;
    const int part = (l & 3) * 8;

    __syncthreads();

    for (int c = 0; c < 12; ++c) {
        const int srcsel = c >> 2;
        const int kl = (c & 3) * 32;

#pragma unroll
        for (int t = 0; t < 2; ++t) {
            const int s = w + t * 4;
            const int row = s * 16 + srow;
            int n = n0 + row; if (n >= N) n = N - 1;
            const ushort* gp;
            if (srcsel == 0)      gp = node_bf + (size_t)n * D + kl + part;
            else if (srcsel == 1) gp = ebar_bf + (size_t)n * D + kl + part;
            else                  gp = u_bf + (size_t)rb[row] * D + kl + part;
            gl_lds16(gp, &As[s * 512]);
        }
#pragma unroll
        for (int t = 0; t < 2; ++t) {
            const int s = w + t * 4;
            const int n = s * 16 + srow;
            gl_lds16(Wt + (size_t)n * 384 + c * 32 + part, &Bs[s * 512]);
        }
        __syncthreads();

        bf16x8 af[4], bfr[4];
#pragma unroll
        for (int i = 0; i < 4; ++i)
            af[i] = *(const bf16x8*)&As[(wm + i * 16 + (l & 15)) * 32 + (l >> 4) * 8];
#pragma unroll
        for (int j = 0; j < 4; ++j)
            bfr[j] = *(const bf16x8*)&Bs[(wn + j * 16 + (l & 15)) * 32 + (l >> 4) * 8];
#pragma unroll
        for (int i = 0; i < 4; ++i)
#pragma unroll
            for (int j = 0; j < 4; ++j)
                acc[i][j] = __builtin_amdgcn_mfma_f32_16x16x32_bf16(af[i], bfr[j], acc[i][j], 0, 0, 0);
        __syncthreads();
    }

#pragma unroll
    for (int i = 0; i < 4; ++i) {
#pragma unroll
        for (int r = 0; r < 4; ++r) {
            const int m = wm + i * 16 + (l >> 4) * 4 + r;
            const int n = n0 + m;
            if (n < N) {
#pragma unroll
                for (int j = 0; j < 4; ++j) {
                    float v = fmaxf(acc[i][j][r] + bj4[j], 0.0f);
                    node_bf[(size_t)n * D + wn + j * 16 + (l & 15)] = f2b(v);
                }
            }
        }
    }
}

// ---------------------------------------------------------------- per-graph sums, phase 1
// block = 128 rows x 128 cols (256 thr: col=tid&127, row-half=tid>>7). batch sorted ->
// each thread flushes a partial per graph transition (~2 atomics/thread).
__global__ void reduce_partial(
    const ushort* __restrict__ node_bf, const ushort* __restrict__ ebar_bf,
    const int* __restrict__ batch,
    float* __restrict__ nsum, float* __restrict__ esum, int N)
{
    const int col = threadIdx.x & 127;
    const int half = threadIdx.x >> 7;
    const int r0 = blockIdx.x * 128;
    float sn = 0.0f, se = 0.0f;
    int cur = -1;
    for (int ri = half; ri < 128; ri += 2) {
        int r = r0 + ri;
        if (r >= N) break;
        int g = batch[r];
        if (g != cur) {
            if (cur >= 0) {
                atomicAdd(&nsum[cur * D + col], sn);
                atomicAdd(&esum[cur * D + col], se);
            }
            cur = g; sn = 0.0f; se = 0.0f;
        }
        sn += b2f(node_bf[(size_t)r * D + col]);
        se += b2f(ebar_bf[(size_t)r * D + col]);
    }
    if (cur >= 0) {
        atomicAdd(&nsum[cur * D + col], sn);
        atomicAdd(&esum[cur * D + col], se);
    }
}

// phase 2: divide by per-graph node count
__global__ void finalize_means(
    const float* __restrict__ nsum, const float* __restrict__ esum,
    const int* __restrict__ batch,
    float* __restrict__ nmean, float* __restrict__ emean, int N)
{
    const int g = blockIdx.x;
    const int j = threadIdx.x;   // 0..127
    __shared__ int cnt_s;
    if (j == 0) {
        int lo = lower_bound_i(batch, N, g);
        int hi = lower_bound_i(batch, N, g + 1);
        cnt_s = hi - lo;
    }
    __syncthreads();
    float inv = 1.0f / (float)max(cnt_s, 1);
    nmean[g * D + j] = nsum[g * D + j] * inv;
    emean[g * D + j] = esum[g * D + j] * inv;
}

// ---------------------------------------------------------------- global update (fp32, tiny) + u_bf refresh
__global__ void global_kernel(
    const float* __restrict__ nmean, const float* __restrict__ emean,
    float* __restrict__ u, ushort* __restrict__ u_bf,
    const float* __restrict__ W, const float* __restrict__ bias)
{
    __shared__ float gin[384];
    const int g = blockIdx.x;
    const int j = threadIdx.x;   // 0..127
    gin[j]       = nmean[g * D + j];
    gin[128 + j] = emean[g * D + j];
    gin[256 + j] = u[g * D + j];
    __syncthreads();
    float s = bias[j];
    for (int k = 0; k < 384; ++k) s += gin[k] * W[(size_t)k * D + j];
    float v = fmaxf(s, 0.0f);
    u[g * D + j] = v;
    u_bf[g * D + j] = f2b(v);
}

// ---------------------------------------------------------------- readout
__global__ void out_kernel(
    const float* __restrict__ nmean, const float* __restrict__ emean,
    const float* __restrict__ u, const int* __restrict__ batch,
    const float* __restrict__ lw, const float* __restrict__ lb,
    float* __restrict__ out, int N, int NC)
{
    __shared__ float pin[384];
    __shared__ int cntg;
    const int g = blockIdx.x;
    const int t = threadIdx.x;   // 0..383
    if (t == 0) {
        int lo = lower_bound_i(batch, N, g);
        int hi = lower_bound_i(batch, N, g + 1);
        cntg = hi - lo;
    }
    __syncthreads();
    if (t < 128)       pin[t] = nmean[g * D + t];
    else if (t < 256)  pin[t] = emean[g * D + (t - 128)];
    else               pin[t] = (cntg > 0) ? u[g * D + (t - 256)] : 0.0f;
    __syncthreads();
    int c = t >> 5, wv = t & 31;
    if (c < NC) {
        float s = 0.0f;
        for (int k = wv; k < 384; k += 32) s += pin[k] * lw[(size_t)k * NC + c];
#pragma unroll
        for (int off = 16; off > 0; off >>= 1) s += __shfl_down(s, off, 32);
        if (wv == 0) out[g * NC + c] = s + lb[c];
    }
}

// ---------------------------------------------------------------- driver
extern "C" void kernel_launch(void* const* d_in, const int* in_sizes, int n_in,
                              void* d_out, int out_size, void* d_ws, size_t ws_size,
                              hipStream_t stream) {
    float* node = (float*)d_in[0];
    float* edge = (float*)d_in[1];
    float* u    = (float*)d_in[2];
    const int* eidx  = (const int*)d_in[3];
    const int* batch = (const int*)d_in[4];
    const float* We_w = (const float*)d_in[5];
    const float* We_b = (const float*)d_in[6];
    const float* Wn_w = (const float*)d_in[7];
    const float* Wn_b = (const float*)d_in[8];
    const float* Wg_w = (const float*)d_in[9];
    const float* Wg_b = (const float*)d_in[10];
    const float* lin_w = (const float*)d_in[11];
    const float* lin_b = (const float*)d_in[12];

    const int N = in_sizes[0] / D;        // 50000
    const int E = in_sizes[3] / 2;        // 600000
    const int G = in_sizes[2] / D;        // 64
    const int NC = out_size / G;          // 10
    const int* src = eidx;
    const int* dst = eidx + E;

    // workspace carve-up (256B-aligned chunks)
    char* p = (char*)d_ws;
    auto carve = [&](size_t bytes) { void* r = p; p += (bytes + 255) & ~(size_t)255; return r; };
    ushort* node_bf = (ushort*)carve((size_t)N * D * 2);
    ushort* ebar_bf = (ushort*)carve((size_t)N * D * 2);
    ushort* u_bf    = (ushort*)carve((size_t)G * D * 2);
    ushort* Wet     = (ushort*)carve((size_t)512 * D * 2);
    ushort* Wnt     = (ushort*)carve((size_t)384 * D * 2);
    int*    cnt     = (int*)carve((size_t)N * 4);
    int*    offs    = (int*)carve((size_t)(N + 1) * 4);
    int*    fill    = (int*)carve((size_t)N * 4);
    int*    csr     = (int*)carve((size_t)E * 4);
    float*  nmean   = (float*)carve((size_t)G * D * 4);
    float*  emean   = (float*)carve((size_t)G * D * 4);
    float*  nsum    = (float*)carve((size_t)G * D * 4);
    float*  esum    = (float*)carve((size_t)G * D * 4);

    ushort* edge_u = (ushort*)edge;  // bf16-in-place, row stride 256 ushorts

    // CSR build (once per call; ws is re-poisoned each call)
    hipMemsetAsync(cnt, 0, (size_t)N * 4, stream);
    hipMemsetAsync(fill, 0, (size_t)N * 4, stream);
    count_kernel<<<(E + 255) / 256, 256, 0, stream>>>(dst, cnt, E);
    scan_kernel<<<1, 1024, 0, stream>>>(cnt, offs, N);
    scatter_kernel<<<(E + 255) / 256, 256, 0, stream>>>(dst, offs, fill, csr, E);

    // bf16 conversions / weight transposes
    f2b_kernel<<<(N * D + 255) / 256, 256, 0, stream>>>(node, node_bf, N * D);
    f2b_kernel<<<(G * D + 255) / 256, 256, 0, stream>>>(u, u_bf, G * D);
    transpose_w<<<(512 * D + 255) / 256, 256, 0, stream>>>(We_w, Wet, 512);
    transpose_w<<<(384 * D + 255) / 256, 256, 0, stream>>>(Wn_w, Wnt, 384);
    conv_edge_kernel<<<(E * 32 + 255) / 256, 256, 0, stream>>>(edge, E);

    const int edge_blocks = (E + 127) / 128;
    const int node_blocks = (N + 127) / 128;
    const int red_blocks  = (N + 127) / 128;

    for (int pass = 0; pass < 3; ++pass) {
        edge_gemm<<<edge_blocks, 256, 0, stream>>>(node_bf, edge_u, u_bf, src, dst, batch,
                                                   Wet, We_b, E);
        gather_ebar<<<(N + 1) / 2, 256, 0, stream>>>(edge_u, offs, csr, ebar_bf, N);
        node_gemm<<<node_blocks, 256, 0, stream>>>(node_bf, ebar_bf, u_bf, batch,
                                                   Wnt, Wn_b, N);
        hipMemsetAsync(nsum, 0, (size_t)G * D * 4, stream);
        hipMemsetAsync(esum, 0, (size_t)G * D * 4, stream);
        reduce_partial<<<red_blocks, 256, 0, stream>>>(node_bf, ebar_bf, batch, nsum, esum, N);
        finalize_means<<<G, 128, 0, stream>>>(nsum, esum, batch, nmean, emean, N);
        global_kernel<<<G, 128, 0, stream>>>(nmean, emean, u, u_bf, Wg_w, Wg_b);
    }
    out_kernel<<<G, 384, 0, stream>>>(nmean, emean, u, batch, lin_w, lin_b,
                                      (float*)d_out, N, NC);
}

// Round 4
// 1239.645 us; speedup vs baseline: 7.6447x; 1.2144x over previous
//
#include <hip/hip_runtime.h>
#include <math.h>

#define D 128

typedef short bf16x8 __attribute__((ext_vector_type(8)));
typedef float f32x4 __attribute__((ext_vector_type(4)));

// ---------------------------------------------------------------- bf16 helpers (RNE)
__device__ __forceinline__ ushort f2b(float f) {
    union { float f; unsigned u; } v; v.f = f;
    unsigned r = v.u + 0x7FFFu + ((v.u >> 16) & 1u);
    return (ushort)(r >> 16);
}
__device__ __forceinline__ float b2f(ushort b) {
    union { unsigned u; float f; } v; v.u = ((unsigned)b) << 16;
    return v.f;
}
// async global->LDS, 16B per lane; LDS dest = wave-uniform base + lane*16
__device__ __forceinline__ void gl_lds16(const void* g, void* l) {
    __builtin_amdgcn_global_load_lds(
        (const __attribute__((address_space(1))) void*)g,
        (__attribute__((address_space(3))) void*)l, 16, 0, 0);
}
__device__ __forceinline__ int lower_bound_i(const int* __restrict__ a, int n, int v) {
    int lo = 0, hi = n;
    while (lo < hi) { int m = (lo + hi) >> 1; if (a[m] < v) lo = m + 1; else hi = m; }
    return lo;
}

// ---------------------------------------------------------------- CSR build (dst fixed per call)
__global__ void count_kernel(const int* __restrict__ dst, int* __restrict__ cnt, int E) {
    int e = blockIdx.x * blockDim.x + threadIdx.x;
    if (e < E) atomicAdd(&cnt[dst[e]], 1);
}

__global__ void scan_kernel(const int* __restrict__ cnt, int* __restrict__ offs, int N) {
    __shared__ int part[1024];
    const int t = threadIdx.x;
    const int chunk = (N + 1023) >> 10;
    int lo = t * chunk; if (lo > N) lo = N;
    int hi = lo + chunk; if (hi > N) hi = N;
    int s = 0;
    for (int i = lo; i < hi; ++i) s += cnt[i];
    part[t] = s;
    __syncthreads();
    if (t == 0) {
        int a = 0;
        for (int i = 0; i < 1024; ++i) { int v = part[i]; part[i] = a; a += v; }
        offs[N] = a;
    }
    __syncthreads();
    int a = part[t];
    for (int i = lo; i < hi; ++i) { offs[i] = a; a += cnt[i]; }
}

__global__ void scatter_kernel(const int* __restrict__ dst, const int* __restrict__ offs,
                               int* __restrict__ fill, int* __restrict__ csr, int E) {
    int e = blockIdx.x * blockDim.x + threadIdx.x;
    if (e < E) {
        int d = dst[e];
        int p = offs[d] + atomicAdd(&fill[d], 1);
        csr[p] = e;
    }
}

// ---------------------------------------------------------------- fused prep:
// [0,c0)  edge fp32->bf16 in-place (row e bf16 in first 256B of 512B slot)
// [c0,c1) node f2b, [c1,c2) u f2b, [c2,c3) We transpose, [c3,c4) Wn transpose
__global__ void prep_kernel(
    float* __restrict__ edge,
    const float* __restrict__ node, ushort* __restrict__ node_bf,
    const float* __restrict__ u, ushort* __restrict__ u_bf,
    const float* __restrict__ We_w, ushort* __restrict__ Wet,
    const float* __restrict__ Wn_w, ushort* __restrict__ Wnt,
    int N, int G, int E)
{
    const int gid = blockIdx.x * 256 + threadIdx.x;
    const int c0 = E * 32;
    const int c1 = c0 + N * D / 4;
    const int c2 = c1 + G * D / 4;
    const int c3 = c2 + 512 * D;
    const int c4 = c3 + 384 * D;
    if (gid < c0) {
        int row = gid >> 5, q = gid & 31;
        float4 v = *(const float4*)(edge + (size_t)row * D + q * 4);
        ushort4 o; o.x = f2b(v.x); o.y = f2b(v.y); o.z = f2b(v.z); o.w = f2b(v.w);
        *(ushort4*)((ushort*)edge + (size_t)row * 256 + q * 4) = o;
    } else if (gid < c1) {
        int i = (gid - c0) * 4;
        float4 v = *(const float4*)(node + i);
        ushort4 o; o.x = f2b(v.x); o.y = f2b(v.y); o.z = f2b(v.z); o.w = f2b(v.w);
        *(ushort4*)(node_bf + i) = o;
    } else if (gid < c2) {
        int i = (gid - c1) * 4;
        float4 v = *(const float4*)(u + i);
        ushort4 o; o.x = f2b(v.x); o.y = f2b(v.y); o.z = f2b(v.z); o.w = f2b(v.w);
        *(ushort4*)(u_bf + i) = o;
    } else if (gid < c3) {
        int i = gid - c2;              // We[k][n] -> Wet[n][k], K=512
        int k = i >> 7, n = i & 127;
        Wet[(size_t)n * 512 + k] = f2b(We_w[i]);
    } else if (gid < c4) {
        int i = gid - c3;              // Wn[k][n] -> Wnt[n][k], K=384
        int k = i >> 7, n = i & 127;
        Wnt[(size_t)n * 384 + k] = f2b(Wn_w[i]);
    }
}

// ---------------------------------------------------------------- edge update GEMM (MFMA bf16)
// tile 256 edges x 128 cols, K=512. 4 waves, each 64 rows x 128 cols (acc[4][8]).
__global__ __launch_bounds__(256, 2) void edge_gemm(
    const ushort* __restrict__ node_bf, ushort* __restrict__ edge_u,
    const ushort* __restrict__ u_bf,
    const int* __restrict__ src, const int* __restrict__ dst,
    const int* __restrict__ batch,
    const ushort* __restrict__ Wt, const float* __restrict__ bias, int E)
{
    __shared__ ushort As[256 * 32];   // 16 KB, [row][32k] contiguous
    __shared__ ushort Bs[128 * 32];   // 8 KB
    __shared__ int rs[256], rd[256], rb[256];

    const int tid = threadIdx.x;
    const int w = tid >> 6, l = tid & 63;
    const int e0 = blockIdx.x * 256;

    {
        int e = e0 + tid; if (e >= E) e = E - 1;
        int s = src[e];
        rs[tid] = s; rd[tid] = dst[e]; rb[tid] = batch[s];
    }

    f32x4 acc[4][8];
#pragma unroll
    for (int i = 0; i < 4; ++i)
#pragma unroll
        for (int j = 0; j < 8; ++j) acc[i][j] = (f32x4)0.0f;

    const int wm = w * 64;             // wave's M offset
    float bj8[8];
#pragma unroll
    for (int j = 0; j < 8; ++j) bj8[j] = bias[j * 16 + (l & 15)];

    const int srow = l >> 2;           // 0..15 within seg
    const int part = (l & 3) * 8;      // ushort offset within 64B row chunk

    __syncthreads();                   // rs/rd/rb visible

    for (int c = 0; c < 16; ++c) {
        const int srcsel = c >> 2;
        const int kl = (c & 3) * 32;   // k offset within source row (ushorts)

#pragma unroll
        for (int t = 0; t < 4; ++t) {  // A: 4 segs of 16 rows per wave (16 segs total)
            const int s = w * 4 + t;
            const int row = s * 16 + srow;
            const ushort* gp;
            if (srcsel == 0)      gp = node_bf + (size_t)rs[row] * D + kl + part;
            else if (srcsel == 1) gp = node_bf + (size_t)rd[row] * D + kl + part;
            else if (srcsel == 2) { int e = e0 + row; if (e >= E) e = E - 1;
                                    gp = edge_u + (size_t)e * 256 + kl + part; }
            else                  gp = u_bf + (size_t)rb[row] * D + kl + part;
            gl_lds16(gp, &As[s * 512]);
        }
#pragma unroll
        for (int t = 0; t < 2; ++t) {  // B: 2 segs of 16 cols per wave (8 segs total)
            const int s = w + t * 4;
            const int n = s * 16 + srow;
            gl_lds16(Wt + (size_t)n * 512 + c * 32 + part, &Bs[s * 512]);
        }
        __syncthreads();               // drains vmcnt -> LDS ready

        bf16x8 af[4], bfr[8];
#pragma unroll
        for (int i = 0; i < 4; ++i)
            af[i] = *(const bf16x8*)&As[(wm + i * 16 + (l & 15)) * 32 + (l >> 4) * 8];
#pragma unroll
        for (int j = 0; j < 8; ++j)
            bfr[j] = *(const bf16x8*)&Bs[(j * 16 + (l & 15)) * 32 + (l >> 4) * 8];
#pragma unroll
        for (int i = 0; i < 4; ++i)
#pragma unroll
            for (int j = 0; j < 8; ++j)
                acc[i][j] = __builtin_amdgcn_mfma_f32_16x16x32_bf16(af[i], bfr[j], acc[i][j], 0, 0, 0);
        __syncthreads();               // compute done before next overwrite
    }

    // epilogue: +bias, relu, bf16 store (C layout: col=lane&15, row=quad*4+r)
#pragma unroll
    for (int i = 0; i < 4; ++i) {
#pragma unroll
        for (int r = 0; r < 4; ++r) {
            const int m = wm + i * 16 + (l >> 4) * 4 + r;
            const int e = e0 + m;
            if (e < E) {
                ushort* ep = edge_u + (size_t)e * 256;
#pragma unroll
                for (int j = 0; j < 8; ++j) {
                    float v = fmaxf(acc[i][j][r] + bj8[j], 0.0f);
                    ep[j * 16 + (l & 15)] = f2b(v);
                }
            }
        }
    }
}

// ---------------------------------------------------------------- ebar gather (CSR, vectorized)
// 8 nodes/block, 32 lanes/node, ushort4 (4 cols) per lane.
__global__ void gather_ebar(const ushort* __restrict__ edge_u, const int* __restrict__ offs,
                            const int* __restrict__ csr, ushort* __restrict__ ebar_bf, int N)
{
    int n = blockIdx.x * 8 + (threadIdx.x >> 5);
    int q = threadIdx.x & 31;
    if (n >= N) return;
    int lo = offs[n], hi = offs[n + 1];
    float s0 = 0.0f, s1 = 0.0f, s2 = 0.0f, s3 = 0.0f;
    for (int j = lo; j < hi; ++j) {
        int e = csr[j];
        ushort4 v = *(const ushort4*)(edge_u + (size_t)e * 256 + q * 4);
        s0 += b2f(v.x); s1 += b2f(v.y); s2 += b2f(v.z); s3 += b2f(v.w);
    }
    float inv = 1.0f / (float)max(hi - lo, 1);
    ushort4 o; o.x = f2b(s0 * inv); o.y = f2b(s1 * inv); o.z = f2b(s2 * inv); o.w = f2b(s3 * inv);
    *(ushort4*)(ebar_bf + (size_t)n * D + q * 4) = o;
}

// ---------------------------------------------------------------- node update GEMM (MFMA bf16), K=384
__global__ __launch_bounds__(256) void node_gemm(
    ushort* __restrict__ node_bf, const ushort* __restrict__ ebar_bf,
    const ushort* __restrict__ u_bf, const int* __restrict__ batch,
    const ushort* __restrict__ Wt, const float* __restrict__ bias, int N)
{
    __shared__ ushort As[128 * 32];
    __shared__ ushort Bs[128 * 32];
    __shared__ int rb[128];

    const int tid = threadIdx.x;
    const int w = tid >> 6, l = tid & 63;
    const int n0 = blockIdx.x * 128;

    if (tid < 128) {
        int n = n0 + tid; if (n >= N) n = N - 1;
        rb[tid] = batch[n];
    }

    f32x4 acc[4][4];
#pragma unroll
    for (int i = 0; i < 4; ++i)
#pragma unroll
        for (int j = 0; j < 4; ++j) acc[i][j] = (f32x4)0.0f;

    const int wm = (w >> 1) * 64, wn = (w & 1) * 64;
    float bj4[4];
#pragma unroll
    for (int j = 0; j < 4; ++j) bj4[j] = bias[wn + j * 16 + (l & 15)];

    const int srow = l >> 2;
    const int part = (l & 3) * 8;

    __syncthreads();

    for (int c = 0; c < 12; ++c) {
        const int srcsel = c >> 2;
        const int kl = (c & 3) * 32;

#pragma unroll
        for (int t = 0; t < 2; ++t) {
            const int s = w + t * 4;
            const int row = s * 16 + srow;
            int n = n0 + row; if (n >= N) n = N - 1;
            const ushort* gp;
            if (srcsel == 0)      gp = node_bf + (size_t)n * D + kl + part;
            else if (srcsel == 1) gp = ebar_bf + (size_t)n * D + kl + part;
            else                  gp = u_bf + (size_t)rb[row] * D + kl + part;
            gl_lds16(gp, &As[s * 512]);
        }
#pragma unroll
        for (int t = 0; t < 2; ++t) {
            const int s = w + t * 4;
            const int n = s * 16 + srow;
            gl_lds16(Wt + (size_t)n * 384 + c * 32 + part, &Bs[s * 512]);
        }
        __syncthreads();

        bf16x8 af[4], bfr[4];
#pragma unroll
        for (int i = 0; i < 4; ++i)
            af[i] = *(const bf16x8*)&As[(wm + i * 16 + (l & 15)) * 32 + (l >> 4) * 8];
#pragma unroll
        for (int j = 0; j < 4; ++j)
            bfr[j] = *(const bf16x8*)&Bs[(wn + j * 16 + (l & 15)) * 32 + (l >> 4) * 8];
#pragma unroll
        for (int i = 0; i < 4; ++i)
#pragma unroll
            for (int j = 0; j < 4; ++j)
                acc[i][j] = __builtin_amdgcn_mfma_f32_16x16x32_bf16(af[i], bfr[j], acc[i][j], 0, 0, 0);
        __syncthreads();
    }

#pragma unroll
    for (int i = 0; i < 4; ++i) {
#pragma unroll
        for (int r = 0; r < 4; ++r) {
            const int m = wm + i * 16 + (l >> 4) * 4 + r;
            const int n = n0 + m;
            if (n < N) {
#pragma unroll
                for (int j = 0; j < 4; ++j) {
                    float v = fmaxf(acc[i][j][r] + bj4[j], 0.0f);
                    node_bf[(size_t)n * D + wn + j * 16 + (l & 15)] = f2b(v);
                }
            }
        }
    }
}

// ---------------------------------------------------------------- per-graph sums, phase 1
__global__ void reduce_partial(
    const ushort* __restrict__ node_bf, const ushort* __restrict__ ebar_bf,
    const int* __restrict__ batch,
    float* __restrict__ nsum, float* __restrict__ esum, int N)
{
    const int col = threadIdx.x & 127;
    const int half = threadIdx.x >> 7;
    const int r0 = blockIdx.x * 128;
    float sn = 0.0f, se = 0.0f;
    int cur = -1;
    for (int ri = half; ri < 128; ri += 2) {
        int r = r0 + ri;
        if (r >= N) break;
        int g = batch[r];
        if (g != cur) {
            if (cur >= 0) {
                atomicAdd(&nsum[cur * D + col], sn);
                atomicAdd(&esum[cur * D + col], se);
            }
            cur = g; sn = 0.0f; se = 0.0f;
        }
        sn += b2f(node_bf[(size_t)r * D + col]);
        se += b2f(ebar_bf[(size_t)r * D + col]);
    }
    if (cur >= 0) {
        atomicAdd(&nsum[cur * D + col], sn);
        atomicAdd(&esum[cur * D + col], se);
    }
}

// ---------------------------------------------------------------- phase 2 + global update fused
// computes means, self-zeros nsum/esum for next pass, updates u (+u_bf)
__global__ void finalize_global(
    float* __restrict__ nsum, float* __restrict__ esum,
    const int* __restrict__ batch,
    float* __restrict__ nmean, float* __restrict__ emean,
    float* __restrict__ u, ushort* __restrict__ u_bf,
    const float* __restrict__ W, const float* __restrict__ bias, int N)
{
    __shared__ float gin[384];
    __shared__ int cnt_s;
    const int g = blockIdx.x;
    const int j = threadIdx.x;   // 0..127
    if (j == 0) {
        int lo = lower_bound_i(batch, N, g);
        int hi = lower_bound_i(batch, N, g + 1);
        cnt_s = hi - lo;
    }
    __syncthreads();
    float inv = 1.0f / (float)max(cnt_s, 1);
    float nm = nsum[g * D + j] * inv;
    float em = esum[g * D + j] * inv;
    nmean[g * D + j] = nm;
    emean[g * D + j] = em;
    nsum[g * D + j] = 0.0f;
    esum[g * D + j] = 0.0f;
    gin[j] = nm; gin[128 + j] = em; gin[256 + j] = u[g * D + j];
    __syncthreads();
    float s = bias[j];
    for (int k = 0; k < 384; ++k) s += gin[k] * W[(size_t)k * D + j];
    float v = fmaxf(s, 0.0f);
    u[g * D + j] = v;
    u_bf[g * D + j] = f2b(v);
}

// ---------------------------------------------------------------- readout
__global__ void out_kernel(
    const float* __restrict__ nmean, const float* __restrict__ emean,
    const float* __restrict__ u, const int* __restrict__ batch,
    const float* __restrict__ lw, const float* __restrict__ lb,
    float* __restrict__ out, int N, int NC)
{
    __shared__ float pin[384];
    __shared__ int cntg;
    const int g = blockIdx.x;
    const int t = threadIdx.x;   // 0..383
    if (t == 0) {
        int lo = lower_bound_i(batch, N, g);
        int hi = lower_bound_i(batch, N, g + 1);
        cntg = hi - lo;
    }
    __syncthreads();
    if (t < 128)       pin[t] = nmean[g * D + t];
    else if (t < 256)  pin[t] = emean[g * D + (t - 128)];
    else               pin[t] = (cntg > 0) ? u[g * D + (t - 256)] : 0.0f;
    __syncthreads();
    int c = t >> 5, wv = t & 31;
    if (c < NC) {
        float s = 0.0f;
        for (int k = wv; k < 384; k += 32) s += pin[k] * lw[(size_t)k * NC + c];
#pragma unroll
        for (int off = 16; off > 0; off >>= 1) s += __shfl_down(s, off, 32);
        if (wv == 0) out[g * NC + c] = s + lb[c];
    }
}

// ---------------------------------------------------------------- driver
extern "C" void kernel_launch(void* const* d_in, const int* in_sizes, int n_in,
                              void* d_out, int out_size, void* d_ws, size_t ws_size,
                              hipStream_t stream) {
    float* node = (float*)d_in[0];
    float* edge = (float*)d_in[1];
    float* u    = (float*)d_in[2];
    const int* eidx  = (const int*)d_in[3];
    const int* batch = (const int*)d_in[4];
    const float* We_w = (const float*)d_in[5];
    const float* We_b = (const float*)d_in[6];
    const float* Wn_w = (const float*)d_in[7];
    const float* Wn_b = (const float*)d_in[8];
    const float* Wg_w = (const float*)d_in[9];
    const float* Wg_b = (const float*)d_in[10];
    const float* lin_w = (const float*)d_in[11];
    const float* lin_b = (const float*)d_in[12];

    const int N = in_sizes[0] / D;        // 50000
    const int E = in_sizes[3] / 2;        // 600000
    const int G = in_sizes[2] / D;        // 64
    const int NC = out_size / G;          // 10
    const int* src = eidx;
    const int* dst = eidx + E;

    // workspace carve-up (256B-aligned chunks); cnt..esum contiguous for single memset
    char* p = (char*)d_ws;
    auto carve = [&](size_t bytes) { void* r = p; p += (bytes + 255) & ~(size_t)255; return r; };
    int*    cnt     = (int*)carve((size_t)N * 4);
    int*    fill    = (int*)carve((size_t)N * 4);
    float*  nsum    = (float*)carve((size_t)G * D * 4);
    float*  esum    = (float*)carve((size_t)G * D * 4);
    size_t  zspan   = (size_t)(p - (char*)cnt);
    int*    offs    = (int*)carve((size_t)(N + 1) * 4);
    int*    csr     = (int*)carve((size_t)E * 4);
    ushort* node_bf = (ushort*)carve((size_t)N * D * 2);
    ushort* ebar_bf = (ushort*)carve((size_t)N * D * 2);
    ushort* u_bf    = (ushort*)carve((size_t)G * D * 2);
    ushort* Wet     = (ushort*)carve((size_t)512 * D * 2);
    ushort* Wnt     = (ushort*)carve((size_t)384 * D * 2);
    float*  nmean   = (float*)carve((size_t)G * D * 4);
    float*  emean   = (float*)carve((size_t)G * D * 4);

    ushort* edge_u = (ushort*)edge;  // bf16-in-place, row stride 256 ushorts

    hipMemsetAsync(cnt, 0, zspan, stream);   // cnt, fill, nsum, esum

    // CSR build (dst fixed per call)
    count_kernel<<<(E + 255) / 256, 256, 0, stream>>>(dst, cnt, E);
    scan_kernel<<<1, 1024, 0, stream>>>(cnt, offs, N);
    scatter_kernel<<<(E + 255) / 256, 256, 0, stream>>>(dst, offs, fill, csr, E);

    // fused conversions / transposes
    const int prep_units = E * 32 + N * D / 4 + G * D / 4 + 512 * D + 384 * D;
    prep_kernel<<<(prep_units + 255) / 256, 256, 0, stream>>>(
        edge, node, node_bf, u, u_bf, We_w, Wet, Wn_w, Wnt, N, G, E);

    const int edge_blocks = (E + 255) / 256;
    const int node_blocks = (N + 127) / 128;
    const int red_blocks  = (N + 127) / 128;

    for (int pass = 0; pass < 3; ++pass) {
        edge_gemm<<<edge_blocks, 256, 0, stream>>>(node_bf, edge_u, u_bf, src, dst, batch,
                                                   Wet, We_b, E);
        gather_ebar<<<(N + 7) / 8, 256, 0, stream>>>(edge_u, offs, csr, ebar_bf, N);
        node_gemm<<<node_blocks, 256, 0, stream>>>(node_bf, ebar_bf, u_bf, batch,
                                                   Wnt, Wn_b, N);
        reduce_partial<<<red_blocks, 256, 0, stream>>>(node_bf, ebar_bf, batch, nsum, esum, N);
        finalize_global<<<G, 128, 0, stream>>>(nsum, esum, batch, nmean, emean,
                                               u, u_bf, Wg_w, Wg_b, N);
    }
    out_kernel<<<G, 384, 0, stream>>>(nmean, emean, u, batch, lin_w, lin_b,
                                      (float*)d_out, N, NC);
}